// Round 11
// baseline (291.339 us; speedup 1.0000x reference)
//
#include <hip/hip_runtime.h>
#include <hip/hip_bf16.h>

#define T_DIM 200
#define U_DIM 100
#define U1    101
#define H_DIM 320
#define K_INNER 512
#define V_DIM 1000
#define B_DIM 4
#define ND 300            // diagonals d = t+u in [0, 299]
#define ROWS 48           // 12 t x 4 u per joint block
#define CHUNK 8           // dp: diagonals per LDS chunk

typedef unsigned short ushort_t;
typedef unsigned char uchar_t;
typedef unsigned int uint32;
typedef long lfrag;       // 8 x fp8 = 2 VGPRs

typedef float ffrag4 __attribute__((ext_vector_type(4)));

#define LOG2E   1.4426950408889634f
#define LOG2E16 (1.4426950408889634f * 0.0625f)   // LOG2E/16 (W2 packed with x16 scale)
#define LN2     0.6931471805599453f

#define AS1 __attribute__((address_space(1)))
#define AS3 __attribute__((address_space(3)))

__device__ __forceinline__ float tanh_fast(float x) {
  float e = __expf(2.0f * x);                 // inf-safe: e=inf -> 1, e=0 -> -1
  return 1.0f - __fdividef(2.0f, e + 1.0f);
}

__device__ __forceinline__ uint2 pk_fp8x8(float t0, float t1, float t2, float t3,
                                          float t4, float t5, float t6, float t7) {
  uint2 r;
  r.x = (uint32)__builtin_amdgcn_cvt_pk_fp8_f32(t0, t1, 0, false);
  r.x = (uint32)__builtin_amdgcn_cvt_pk_fp8_f32(t2, t3, (int)r.x, true);
  r.y = (uint32)__builtin_amdgcn_cvt_pk_fp8_f32(t4, t5, 0, false);
  r.y = (uint32)__builtin_amdgcn_cvt_pk_fp8_f32(t6, t7, (int)r.y, true);
  return r;
}

// lane i <- lane i-1 (wave_shr:1 DPP, VALU-speed); invalid lane 0 gets `oldv`
__device__ __forceinline__ float dpp_up1(float v, float oldv) {
  return __int_as_float(__builtin_amdgcn_update_dpp(
      __float_as_int(oldv), __float_as_int(v), 0x138, 0xf, 0xf, false));
}

// ---------------- prep (unchanged from r10): hproj x2 + W2 tile-pack fp8 x16
__global__ __launch_bounds__(512)
void prep_kernel(const float* __restrict__ enc, const float* __restrict__ dec,
                 const float* __restrict__ W1, const float* __restrict__ W2,
                 float* __restrict__ hEnc, float* __restrict__ hDec,
                 uchar_t* __restrict__ W2f8)
{
  __shared__ union { float sIn[8][H_DIM]; float sW[8][1024]; } sh;
  const int tid = threadIdx.x;
  const int blk = blockIdx.x;

  if (blk < 151) {
    const float* inp; float* outp; int nRows, rowOff, b0;
    if (blk < 100) { inp = enc; outp = hEnc; nRows = B_DIM * T_DIM; rowOff = 0;     b0 = blk; }
    else           { inp = dec; outp = hDec; nRows = B_DIM * U1;    rowOff = H_DIM; b0 = blk - 100; }
    const int r0 = b0 * 8;
    for (int i = tid; i < 8 * H_DIM; i += 512) {
      int r = i / H_DIM, k = i - r * H_DIM;
      int rr = r0 + r;
      sh.sIn[r][k] = (rr < nRows) ? inp[(size_t)rr * H_DIM + k] : 0.0f;
    }
    __syncthreads();
    const int c = tid;
    float acc[8];
#pragma unroll
    for (int r = 0; r < 8; ++r) acc[r] = 0.0f;
    const float* Wp = W1 + (size_t)rowOff * K_INNER + c;
    for (int k = 0; k < H_DIM; k += 4) {
      float w0 = Wp[(size_t)(k + 0) * K_INNER];
      float w1 = Wp[(size_t)(k + 1) * K_INNER];
      float w2 = Wp[(size_t)(k + 2) * K_INNER];
      float w3 = Wp[(size_t)(k + 3) * K_INNER];
#pragma unroll
      for (int r = 0; r < 8; ++r) {
        float4 s = *(const float4*)&sh.sIn[r][k];
        acc[r] = fmaf(s.w, w3, fmaf(s.z, w2, fmaf(s.y, w1, fmaf(s.x, w0, acc[r]))));
      }
    }
#pragma unroll
    for (int r = 0; r < 8; ++r) {
      int rr = r0 + r;
      if (rr < nRows) outp[(size_t)rr * K_INNER + c] = acc[r];
    }
  } else {
    // W2 tile-pack (x16 scale; raw weights sit in e4m3 denormal zone):
    // byte off = (ct*16+ks)*8192 + w*2048 + q*512 + col*8
    const int kc = blk - 151;
    for (int i = tid; i < 8 * 1024; i += 512) {
      int r = i >> 10, n = i & 1023;
      sh.sW[r][n] = (n < V_DIM) ? W2[(size_t)(kc * 8 + r) * V_DIM + n] : 0.0f;
    }
    __syncthreads();
    const int ks = kc >> 2, q = kc & 3;
#pragma unroll
    for (int h = 0; h < 2; ++h) {
      int n = tid + h * 512;
      uint2 pk = pk_fp8x8(sh.sW[0][n] * 16.f, sh.sW[1][n] * 16.f,
                          sh.sW[2][n] * 16.f, sh.sW[3][n] * 16.f,
                          sh.sW[4][n] * 16.f, sh.sW[5][n] * 16.f,
                          sh.sW[6][n] * 16.f, sh.sW[7][n] * 16.f);
      const int ct = n >> 8, w = (n >> 6) & 3, col = n & 63;
      const size_t off = (size_t)(ct * 16 + ks) * 8192 + w * 2048 + q * 512 + col * 8;
      *(uint2*)&W2f8[off] = pk;
    }
  }
}

// ---------------- xgen: X = tanh(e+d+b1) -> fp8 global (rotation baked) +
// raw blank/label logits via fp32 dots (removes tanh AND label/blank selects
// from the issue-saturated joint kernel -- r8-r10 invariant: MfmaUtil+VALUBusy
// ~90%, only instruction removal helps).
// Block = (u, b); wave w handles rows t = 4i+w (t&1 = w&1 -> rotation per-thread const).
__global__ __launch_bounds__(256)
void xgen_kernel(const float* __restrict__ hEnc, const float* __restrict__ hDec,
                 const float* __restrict__ b1, const float* __restrict__ W2,
                 const float* __restrict__ b2, const int* __restrict__ tokens,
                 uchar_t* __restrict__ Xg, float* __restrict__ pBL)
{
  const int u = blockIdx.x;          // 0..100
  const int b = blockIdx.y;
  const int tid = threadIdx.x;
  const int w = tid >> 6, lane = tid & 63;
  const int k0 = lane * 8;
  const int tok = (u < U_DIM) ? tokens[b * U_DIM + u] : 0;

  float dR[8], wB[8], wL[8];
  const float* dptr = hDec + (size_t)(b * U1 + u) * K_INNER + k0;
#pragma unroll
  for (int j = 0; j < 8; ++j) dR[j] = dptr[j] + b1[k0 + j];
#pragma unroll
  for (int j = 0; j < 8; ++j) {
    wB[j] = W2[(size_t)(k0 + j) * V_DIM];
    wL[j] = W2[(size_t)(k0 + j) * V_DIM + tok];
  }
  const float b2b = b2[0], b2l = b2[tok];
  const int x7r = ((w & 1) << 2) | (u & 3);
  const int slotoff = (lane ^ x7r) << 3;     // per-thread constant

#pragma unroll 2
  for (int i = 0; i < 50; ++i) {
    const int t = i * 4 + w;                  // always < 200
    const float* er = hEnc + (size_t)(b * T_DIM + t) * K_INNER + k0;
    float4 e0 = *(const float4*)er;
    float4 e1 = *(const float4*)(er + 4);
    float x0 = tanh_fast(e0.x + dR[0]);
    float x1 = tanh_fast(e0.y + dR[1]);
    float x2 = tanh_fast(e0.z + dR[2]);
    float x3 = tanh_fast(e0.w + dR[3]);
    float x4 = tanh_fast(e1.x + dR[4]);
    float x5 = tanh_fast(e1.y + dR[5]);
    float x6 = tanh_fast(e1.z + dR[6]);
    float x7 = tanh_fast(e1.w + dR[7]);
    uint2 pk = pk_fp8x8(x0, x1, x2, x3, x4, x5, x6, x7);
    *(uint2*)&Xg[((size_t)(b * T_DIM + t) * U1 + u) * 512 + slotoff] = pk;
    float db = x0 * wB[0];
    db = fmaf(x1, wB[1], db); db = fmaf(x2, wB[2], db); db = fmaf(x3, wB[3], db);
    db = fmaf(x4, wB[4], db); db = fmaf(x5, wB[5], db); db = fmaf(x6, wB[6], db);
    db = fmaf(x7, wB[7], db);
    float dl = x0 * wL[0];
    dl = fmaf(x1, wL[1], dl); dl = fmaf(x2, wL[2], dl); dl = fmaf(x3, wL[3], dl);
    dl = fmaf(x4, wL[4], dl); dl = fmaf(x5, wL[5], dl); dl = fmaf(x6, wL[6], dl);
    dl = fmaf(x7, wL[7], dl);
#pragma unroll
    for (int m = 1; m < 64; m <<= 1) {
      db += __shfl_xor(db, m, 64);
      dl += __shfl_xor(dl, m, 64);
    }
    if (lane == 0) {
      const int d = t + u;
      float2* o = (float2*)&pBL[((size_t)(b * ND + d) * 128 + u) * 2];
      *o = make_float2((db + b2b) * LOG2E, (dl + b2l) * LOG2E);
    }
  }
}

// ---------------- joint: pure fp8 GEMM + sum(exp) -> lse plane.
// A-tile DMA'd from pre-tanh'd X (24 x 1KB issues, zero staging VALU); B via
// r10's per-wave DMA double-buffer (vmcnt(2)). (256,4), LDS 40KB -> 4 blocks/CU.
// Tripwire: WRITE_SIZE balloon => spill => revert to (256,3).
__global__ __launch_bounds__(256, 4)
void joint_kernel(const uchar_t* __restrict__ Xg, const uchar_t* __restrict__ W2f8,
                  const float* __restrict__ b2, float* __restrict__ pL)
{
  __shared__ union SU {
    uchar_t X[ROWS * 512];        // 48 rows x 512 fp8, granule rotation baked (24KB)
    float red[4][ROWS];
  } sh;
  __shared__ __align__(16) uchar_t sB[4][2][2048];   // per-wave B double buffer (16KB)

  const int tid = threadIdx.x;
  const int b  = blockIdx.z;
  const int t0 = blockIdx.y * 12;
  const int u0 = blockIdx.x * 4;
  const int wave = tid >> 6;
  const int lane = tid & 63;
  const int l15 = lane & 15;
  const int quad = lane >> 4;

  // b2 preload (retires at the staging barrier -> K-loop vmcnt sees only my DMA)
  float b2s[4][4];
#pragma unroll
  for (int ct = 0; ct < 4; ++ct)
#pragma unroll
    for (int cb = 0; cb < 4; ++cb) {
      int v = ct * 256 + wave * 64 + cb * 16 + l15;
      b2s[ct][cb] = (v < V_DIM) ? b2[v] * LOG2E : -1e30f;
    }

  // ---- A-tile DMA: 24 x 1KB issues (6 per wave); t clamped (garbage rows are
  // row-isolated and their outputs guarded)
#pragma unroll
  for (int j = 0; j < 6; ++j) {
    const int idx = wave * 6 + j;
    const int tt = idx >> 1, h = idx & 1;
    const int t = min(t0 + tt, T_DIM - 1);
    const uchar_t* g = Xg + ((size_t)(b * T_DIM + t) * U1 + u0) * 512 + h * 1024 + (size_t)lane * 16;
    __builtin_amdgcn_global_load_lds((const AS1 void*)g,
                                     (AS3 void*)&sh.X[tt * 2048 + h * 1024], 16, 0, 0);
  }

  uchar_t* sBw = &sB[wave][0][0];
  const uchar_t* gW = W2f8 + (size_t)wave * 2048 + (size_t)lane * 16;
#define STAGE(gbase, bufv)                                                          \
  {                                                                                 \
    __builtin_amdgcn_global_load_lds(                                               \
        (const AS1 void*)(gbase),                                                   \
        (AS3 void*)(sBw + (bufv) * 2048), 16, 0, 0);                                \
    __builtin_amdgcn_global_load_lds(                                               \
        (const AS1 void*)((gbase) + 1024),                                          \
        (AS3 void*)(sBw + (bufv) * 2048 + 1024), 16, 0, 0);                         \
  }
  STAGE(gW, 0)
  const uchar_t* gP = gW + 8192;
  __syncthreads();   // drains vmcnt(0): A tile + B stage0 resident

  // A addressing: granule g = quad+4ks stored at slot g ^ (m&7), m&7 = l15&7.
  // (g^x7)<<3 splits into disjoint-bit parts: (quad^(x7&3))<<3  +  (32ks ^ ((x7&4)<<3))
  const int x7 = l15 & 7;
  const uchar_t* aL2 = &sh.X[l15 * 512 + ((quad ^ (x7 & 3)) << 3)];
  const int x74s = (x7 & 4) << 3;
  const uchar_t* bL = sBw + quad * 512 + l15 * 8;

  float sumexp[3][4];
#pragma unroll
  for (int i = 0; i < 3; ++i)
#pragma unroll
    for (int j = 0; j < 4; ++j) sumexp[i][j] = 0.0f;

#pragma unroll 1
  for (int ct = 0; ct < 4; ++ct) {
    ffrag4 acc[3][4];
    ffrag4 zero4 = {0.0f, 0.0f, 0.0f, 0.0f};
#pragma unroll
    for (int rb = 0; rb < 3; ++rb)
#pragma unroll
      for (int cb = 0; cb < 4; ++cb) acc[rb][cb] = zero4;

#pragma unroll
    for (int ks = 0; ks < 16; ++ks) {
      if (ct < 3 || ks < 15) {
        STAGE(gP, (ks + 1) & 1)
        gP += 8192;
        asm volatile("s_waitcnt vmcnt(2)" ::: "memory");
      } else {
        asm volatile("s_waitcnt vmcnt(0)" ::: "memory");
      }
      const int aoff = (32 * ks) ^ x74s;
      lfrag av[3];
      av[0] = *(const lfrag*)(aL2 + aoff);
      av[1] = *(const lfrag*)(aL2 + aoff + 8192);
      av[2] = *(const lfrag*)(aL2 + aoff + 16384);
      const uchar_t* bk = bL + ((ks & 1) << 11);
      lfrag bv[4];
#pragma unroll
      for (int cb = 0; cb < 4; ++cb)
        bv[cb] = *(const lfrag*)(bk + cb * 128);
#pragma unroll
      for (int rb = 0; rb < 3; ++rb)
#pragma unroll
        for (int cb = 0; cb < 4; ++cb)
          acc[rb][cb] = __builtin_amdgcn_mfma_f32_16x16x32_fp8_fp8(av[rb], bv[cb], acc[rb][cb], 0, 0, 0);
    }

    // epilogue: sumexp only (acc = 16 x true logit)
#pragma unroll
    for (int cb = 0; cb < 4; ++cb) {
      const float bs = b2s[ct][cb];
#pragma unroll
      for (int rb = 0; rb < 3; ++rb)
#pragma unroll
        for (int reg = 0; reg < 4; ++reg)
          sumexp[rb][reg] += exp2f(fmaf(acc[rb][cb][reg], LOG2E16, bs));
    }
  }
#undef STAGE

#pragma unroll
  for (int mask = 1; mask <= 8; mask <<= 1)
#pragma unroll
    for (int rb = 0; rb < 3; ++rb)
#pragma unroll
      for (int reg = 0; reg < 4; ++reg)
        sumexp[rb][reg] += __shfl_xor(sumexp[rb][reg], mask, 64);

  __syncthreads();   // X reads done -> reuse union as red[]
  if (l15 == 0) {
#pragma unroll
    for (int rb = 0; rb < 3; ++rb)
#pragma unroll
      for (int reg = 0; reg < 4; ++reg)
        sh.red[wave][rb * 16 + quad * 4 + reg] = sumexp[rb][reg];
  }
  __syncthreads();
  if (tid < ROWS) {
    float S = sh.red[0][tid] + sh.red[1][tid] + sh.red[2][tid] + sh.red[3][tid];
    int t = t0 + (tid >> 2);
    int u = u0 + (tid & 3);
    if (t < T_DIM && u < U1)
      pL[(size_t)(b * ND + t + u) * 128 + u] = __log2f(S);
  }
}

// ---------------- RNNT DP: two planes (raw bl/lb + lse), LDS DMA triple-buffer,
// batched chunk reads, DPP serial shuffles. log-probs formed on the fly:
// B = raw - lse, L = raw_l - lse.
__global__ __launch_bounds__(256)
void dp_kernel(const float* __restrict__ pBL, const float* __restrict__ pL,
               const int* __restrict__ outLen, const int* __restrict__ tokLen,
               float* __restrict__ outLoss)
{
  __shared__ __align__(16) float sA[4][3][CHUNK * 256];   // 96 KB
  __shared__ __align__(16) float sL[4][3][CHUNK * 128];   // 48 KB
  __shared__ float llsh[B_DIM];
  const int tid = threadIdx.x;
  const int wv = tid >> 6;
  const int lane = tid & 63;
  const float* srcA = pBL + (size_t)wv * ND * 256;
  const float* srcL = pL  + (size_t)wv * ND * 128;
  const int tIdx = outLen[wv] - 1;
  const int uIdx = tokLen[wv];
  const int dStar = tIdx + uIdx;
  const float NEG = -1e30f;
  const float blkStar = srcA[((size_t)dStar * 128 + uIdx) * 2]
                      - srcL[(size_t)dStar * 128 + uIdx];

  float aE = (lane == 0) ? 0.0f : NEG;
  float aO = NEG;
  float ll2 = 0.0f;
  if (dStar == 0 && lane == 0) ll2 = blkStar;

  const int uE = 2 * lane;

#define ISSUE(c, buf)                                                          \
  {                                                                            \
    const float* gA_ = srcA + (size_t)(c) * (CHUNK * 256);                     \
    const float* gL_ = srcL + (size_t)(c) * (CHUNK * 128);                     \
    float* lA_ = &sA[wv][(buf)][0];                                            \
    float* lL_ = &sL[wv][(buf)][0];                                            \
    _Pragma("unroll")                                                          \
    for (int j_ = 0; j_ < CHUNK; ++j_)                                         \
      __builtin_amdgcn_global_load_lds(                                        \
        (const AS1 void*)(gA_ + j_ * 256 + lane * 4),                          \
        (AS3 void*)(lA_ + j_ * 256), 16, 0, 0);                                \
    _Pragma("unroll")                                                          \
    for (int j_ = 0; j_ < 4; ++j_)                                             \
      __builtin_amdgcn_global_load_lds(                                        \
        (const AS1 void*)(gL_ + j_ * 256 + lane * 4),                          \
        (AS3 void*)(lL_ + j_ * 256), 16, 0, 0);                                \
  }

  ISSUE(0, 0)
  ISSUE(1, 1)
#pragma unroll 1
  for (int c = 0; c < 38; ++c) {
    { const int nc = c + 2; const int cc = nc <= 37 ? nc : 37; ISSUE(cc, nc % 3) }
    asm volatile("s_waitcnt vmcnt(24)" ::: "memory");   // chunk c resident
    const float* bufA = &sA[wv][c % 3][0];
    const float* bufL = &sL[wv][c % 3][0];
    float4 qv[CHUNK];
    float2 lv[CHUNK];
#pragma unroll
    for (int j = 0; j < CHUNK; ++j) {
      qv[j] = *(const float4*)&bufA[j * 256 + uE * 2];
      lv[j] = *(const float2*)&bufL[j * 128 + uE];
    }
#pragma unroll
    for (int j = 0; j < CHUNK; ++j) {
      const int d = c * CHUNK + 1 + j;
      float4 q = qv[j]; float2 lz = lv[j];
      float BE = q.x - lz.x, LE = q.y - lz.x;
      float BO = q.z - lz.y, LO = q.w - lz.y;
      float aO_up = dpp_up1(aO, NEG);
      float labUp = dpp_up1(LO, NEG);                 // L[uE-1] @ d-1
      float bt0 = aE + BE, lt0 = aO_up + labUp;
      float mx0 = fmaxf(bt0, lt0), mn0 = fminf(bt0, lt0);
      float r0 = mx0 + __log2f(1.0f + exp2f(mn0 - mx0));
      int te = d - uE;
      float nE = ((uE <= U_DIM) && (te >= 0) && (te < T_DIM)) ? r0 : NEG;
      float bt1 = aO + BO, lt1 = aE + LE;
      float mx1 = fmaxf(bt1, lt1), mn1 = fminf(bt1, lt1);
      float r1 = mx1 + __log2f(1.0f + exp2f(mn1 - mx1));
      int to = te - 1;
      float nO = ((uE + 1 <= U_DIM) && (to >= 0) && (to < T_DIM)) ? r1 : NEG;
      aE = nE; aO = nO;
      if (d == dStar) {
        if (uIdx == uE)          ll2 = nE + blkStar;
        else if (uIdx == uE + 1) ll2 = nO + blkStar;
      }
    }
  }
#undef ISSUE

#pragma unroll
  for (int mask = 1; mask < 64; mask <<= 1) ll2 += __shfl_xor(ll2, mask, 64);
  if (lane == 0) llsh[wv] = ll2;
  __syncthreads();
  if (tid == 0)
    outLoss[0] = -(llsh[0] + llsh[1] + llsh[2] + llsh[3]) * 0.25f * LN2;
}

// ---------------- launch
extern "C" void kernel_launch(void* const* d_in, const int* in_sizes, int n_in,
                              void* d_out, int out_size, void* d_ws, size_t ws_size,
                              hipStream_t stream)
{
  const float* enc    = (const float*)d_in[0];
  const float* dec    = (const float*)d_in[1];
  const int*   tokens = (const int*)d_in[2];
  const int*   outLen = (const int*)d_in[3];
  const int*   tokLen = (const int*)d_in[4];
  const float* W1     = (const float*)d_in[5];
  const float* b1     = (const float*)d_in[6];
  const float* W2     = (const float*)d_in[7];
  const float* b2     = (const float*)d_in[8];
  float* out = (float*)d_out;

  char* ws = (char*)d_ws;
  float*   hEnc = (float*)(ws + 0);            // 1,638,400
  float*   hDec = (float*)(ws + 1638400);      //   827,392
  uchar_t* W2f8 = (uchar_t*)(ws + 2465792);    //   524,288
  uchar_t* Xg   = (uchar_t*)(ws + 2990080);    // 41,369,600 (+4KB clamp-overread pad)
  float*   pBL  = (float*)(ws + 44363776);     // 1,228,800
  float*   pL   = (float*)(ws + 45592576);     //   614,400 (+16KB dp overread pad)
  // total needed ~46.3 MB

  prep_kernel<<<dim3(215), dim3(512), 0, stream>>>(enc, dec, W1, W2, hEnc, hDec, W2f8);
  xgen_kernel<<<dim3(101, B_DIM), dim3(256), 0, stream>>>(hEnc, hDec, b1, W2, b2, tokens, Xg, pBL);
  joint_kernel<<<dim3(26, 17, B_DIM), dim3(256), 0, stream>>>(Xg, W2f8, b2, pL);
  dp_kernel<<<dim3(1), dim3(256), 0, stream>>>(pBL, pL, outLen, tokLen, out);
}

// Round 12
// 263.960 us; speedup vs baseline: 1.1037x; 1.1037x over previous
//
#include <hip/hip_runtime.h>
#include <hip/hip_bf16.h>

#define T_DIM 200
#define U_DIM 100
#define U1    101
#define H_DIM 320
#define K_INNER 512
#define V_DIM 1000
#define B_DIM 4
#define ND 300            // diagonals d = t+u in [0, 299]
#define ROWS 48           // 12 t x 4 u per joint block
#define CHUNK 8           // dp: diagonals per LDS chunk

typedef unsigned short ushort_t;
typedef unsigned char uchar_t;
typedef unsigned int uint32;
typedef long lfrag;       // 8 x fp8 = 2 VGPRs

typedef float ffrag4 __attribute__((ext_vector_type(4)));

#define LOG2E   1.4426950408889634f
#define LOG2E16 (1.4426950408889634f * 0.0625f)   // LOG2E/16 (W2 packed with x16 scale)
#define LN2     0.6931471805599453f

#define AS1 __attribute__((address_space(1)))
#define AS3 __attribute__((address_space(3)))

__device__ __forceinline__ float tanh_fast(float x) {
  float e = __expf(2.0f * x);                 // inf-safe: e=inf -> 1, e=0 -> -1
  return 1.0f - __fdividef(2.0f, e + 1.0f);
}

__device__ __forceinline__ uint2 pk_fp8x8(float t0, float t1, float t2, float t3,
                                          float t4, float t5, float t6, float t7) {
  uint2 r;
  r.x = (uint32)__builtin_amdgcn_cvt_pk_fp8_f32(t0, t1, 0, false);
  r.x = (uint32)__builtin_amdgcn_cvt_pk_fp8_f32(t2, t3, (int)r.x, true);
  r.y = (uint32)__builtin_amdgcn_cvt_pk_fp8_f32(t4, t5, 0, false);
  r.y = (uint32)__builtin_amdgcn_cvt_pk_fp8_f32(t6, t7, (int)r.y, true);
  return r;
}

// lane i <- lane i-1 (wave_shr:1 DPP, VALU-speed); invalid lane 0 gets `oldv`
__device__ __forceinline__ float dpp_up1(float v, float oldv) {
  return __int_as_float(__builtin_amdgcn_update_dpp(
      __float_as_int(oldv), __float_as_int(v), 0x138, 0xf, 0xf, false));
}

// ---------------- prep: hproj x2 + W2 tile-pack fp8 x16 (unchanged)
__global__ __launch_bounds__(512)
void prep_kernel(const float* __restrict__ enc, const float* __restrict__ dec,
                 const float* __restrict__ W1, const float* __restrict__ W2,
                 float* __restrict__ hEnc, float* __restrict__ hDec,
                 uchar_t* __restrict__ W2f8)
{
  __shared__ union { float sIn[8][H_DIM]; float sW[8][1024]; } sh;
  const int tid = threadIdx.x;
  const int blk = blockIdx.x;

  if (blk < 151) {
    const float* inp; float* outp; int nRows, rowOff, b0;
    if (blk < 100) { inp = enc; outp = hEnc; nRows = B_DIM * T_DIM; rowOff = 0;     b0 = blk; }
    else           { inp = dec; outp = hDec; nRows = B_DIM * U1;    rowOff = H_DIM; b0 = blk - 100; }
    const int r0 = b0 * 8;
    for (int i = tid; i < 8 * H_DIM; i += 512) {
      int r = i / H_DIM, k = i - r * H_DIM;
      int rr = r0 + r;
      sh.sIn[r][k] = (rr < nRows) ? inp[(size_t)rr * H_DIM + k] : 0.0f;
    }
    __syncthreads();
    const int c = tid;
    float acc[8];
#pragma unroll
    for (int r = 0; r < 8; ++r) acc[r] = 0.0f;
    const float* Wp = W1 + (size_t)rowOff * K_INNER + c;
    for (int k = 0; k < H_DIM; k += 4) {
      float w0 = Wp[(size_t)(k + 0) * K_INNER];
      float w1 = Wp[(size_t)(k + 1) * K_INNER];
      float w2 = Wp[(size_t)(k + 2) * K_INNER];
      float w3 = Wp[(size_t)(k + 3) * K_INNER];
#pragma unroll
      for (int r = 0; r < 8; ++r) {
        float4 s = *(const float4*)&sh.sIn[r][k];
        acc[r] = fmaf(s.w, w3, fmaf(s.z, w2, fmaf(s.y, w1, fmaf(s.x, w0, acc[r]))));
      }
    }
#pragma unroll
    for (int r = 0; r < 8; ++r) {
      int rr = r0 + r;
      if (rr < nRows) outp[(size_t)rr * K_INNER + c] = acc[r];
    }
  } else {
    // W2 tile-pack (x16 scale; raw weights sit in e4m3 denormal zone):
    // byte off = (ct*16+ks)*8192 + w*2048 + q*512 + col*8
    const int kc = blk - 151;
    for (int i = tid; i < 8 * 1024; i += 512) {
      int r = i >> 10, n = i & 1023;
      sh.sW[r][n] = (n < V_DIM) ? W2[(size_t)(kc * 8 + r) * V_DIM + n] : 0.0f;
    }
    __syncthreads();
    const int ks = kc >> 2, q = kc & 3;
#pragma unroll
    for (int h = 0; h < 2; ++h) {
      int n = tid + h * 512;
      uint2 pk = pk_fp8x8(sh.sW[0][n] * 16.f, sh.sW[1][n] * 16.f,
                          sh.sW[2][n] * 16.f, sh.sW[3][n] * 16.f,
                          sh.sW[4][n] * 16.f, sh.sW[5][n] * 16.f,
                          sh.sW[6][n] * 16.f, sh.sW[7][n] * 16.f);
      const int ct = n >> 8, w = (n >> 6) & 3, col = n & 63;
      const size_t off = (size_t)(ct * 16 + ks) * 8192 + w * 2048 + q * 512 + col * 8;
      *(uint2*)&W2f8[off] = pk;
    }
  }
}

// ---------------- xgen: PURE tanh+pack, wave-per-row (r11 post-mortem: the
// 50-iter serial loop with 12 shfl/iter at 1.6 blocks/CU cost ~70us; this shape
// is embarrassingly parallel: 80800 waves, coalesced 2KB loads, 512B store,
// zero cross-lane ops -> ~6us issue-bound).
__global__ __launch_bounds__(256)
void xgen_kernel(const float* __restrict__ hEnc, const float* __restrict__ hDec,
                 const float* __restrict__ b1, uchar_t* __restrict__ Xg)
{
  const int gw = blockIdx.x * 4 + (threadIdx.x >> 6);   // row = (b,t,u)
  const int lane = threadIdx.x & 63;
  const int b = gw / (T_DIM * U1);
  const int rem = gw - b * (T_DIM * U1);
  const int t = rem / U1;
  const int u = rem - t * U1;
  const int k0 = lane * 8;

  const float* er = hEnc + (size_t)(b * T_DIM + t) * K_INNER + k0;
  const float* dr = hDec + (size_t)(b * U1 + u) * K_INNER + k0;
  float4 e0 = *(const float4*)er;
  float4 e1 = *(const float4*)(er + 4);
  float4 d0 = *(const float4*)dr;
  float4 d1 = *(const float4*)(dr + 4);
  float4 c0 = *(const float4*)(b1 + k0);
  float4 c1 = *(const float4*)(b1 + k0 + 4);
  uint2 pk = pk_fp8x8(tanh_fast(e0.x + d0.x + c0.x), tanh_fast(e0.y + d0.y + c0.y),
                      tanh_fast(e0.z + d0.z + c0.z), tanh_fast(e0.w + d0.w + c0.w),
                      tanh_fast(e1.x + d1.x + c1.x), tanh_fast(e1.y + d1.y + c1.y),
                      tanh_fast(e1.z + d1.z + c1.z), tanh_fast(e1.w + d1.w + c1.w));
  // bake joint's granule rotation: slot = lane ^ (m&7), m&7 = ((t&1)<<2)|(u&3)
  const int slotoff = (lane ^ (((t & 1) << 2) | (u & 3))) << 3;
  *(uint2*)&Xg[((size_t)(b * T_DIM + t) * U1 + u) * 512 + slotoff] = pk;
}

// ---------------- joint: fp8 GEMM (A DMA from Xg, B DMA double-buffer) +
// sumexp + label/blank extraction in-epilogue (r12: moved back from xgen --
// ~400 VALU/wave of selects is cheaper than xgen's shfl-chain dots).
// (256,3): no spill AND clean vmcnt accounting (r11's (256,4) spill polluted
// the DMA counter with scratch buffer-ops).
__global__ __launch_bounds__(256, 3)
void joint_kernel(const uchar_t* __restrict__ Xg, const uchar_t* __restrict__ W2f8,
                  const float* __restrict__ b2, const int* __restrict__ tokens,
                  float* __restrict__ pD)
{
  __shared__ union SU {
    uchar_t X[ROWS * 512];        // 48 rows x 512 fp8, granule rotation baked (24KB)
    float red[4][ROWS][4];
  } sh;
  __shared__ __align__(16) uchar_t sB[4][2][2048];   // per-wave B double buffer (16KB)

  const int tid = threadIdx.x;
  const int b  = blockIdx.z;
  const int t0 = blockIdx.y * 12;
  const int u0 = blockIdx.x * 4;
  const int wave = tid >> 6;
  const int lane = tid & 63;
  const int l15 = lane & 15;
  const int quad = lane >> 4;

  // preloads retire at the staging barrier -> K-loop vmcnt sees only my DMA
  float b2s[4][4];
#pragma unroll
  for (int ct = 0; ct < 4; ++ct)
#pragma unroll
    for (int cb = 0; cb < 4; ++cb) {
      int v = ct * 256 + wave * 64 + cb * 16 + l15;
      b2s[ct][cb] = (v < V_DIM) ? b2[v] * LOG2E : -1e30f;
    }
  int tokv[4];
#pragma unroll
  for (int j = 0; j < 4; ++j)
    tokv[j] = (u0 + j < U_DIM) ? tokens[b * U_DIM + u0 + j] : -1;

  // ---- A-tile DMA: 24 x 1KB issues (6 per wave)
#pragma unroll
  for (int j = 0; j < 6; ++j) {
    const int idx = wave * 6 + j;
    const int tt = idx >> 1, h = idx & 1;
    const int t = min(t0 + tt, T_DIM - 1);
    const uchar_t* g = Xg + ((size_t)(b * T_DIM + t) * U1 + u0) * 512 + h * 1024 + (size_t)lane * 16;
    __builtin_amdgcn_global_load_lds((const AS1 void*)g,
                                     (AS3 void*)&sh.X[tt * 2048 + h * 1024], 16, 0, 0);
  }

  uchar_t* sBw = &sB[wave][0][0];
  const uchar_t* gW = W2f8 + (size_t)wave * 2048 + (size_t)lane * 16;
#define STAGE(gbase, bufv)                                                          \
  {                                                                                 \
    __builtin_amdgcn_global_load_lds(                                               \
        (const AS1 void*)(gbase),                                                   \
        (AS3 void*)(sBw + (bufv) * 2048), 16, 0, 0);                                \
    __builtin_amdgcn_global_load_lds(                                               \
        (const AS1 void*)((gbase) + 1024),                                          \
        (AS3 void*)(sBw + (bufv) * 2048 + 1024), 16, 0, 0);                         \
  }
  STAGE(gW, 0)
  const uchar_t* gP = gW + 8192;
  __syncthreads();   // drains vmcnt(0): A tile + B stage0 resident

  // A addressing: granule g = quad+4ks at slot g ^ (m&7); split into constant
  // (quad^(x7&3))<<3 and per-ks (32ks ^ ((x7&4)<<3))
  const int x7 = l15 & 7;
  const uchar_t* aL2 = &sh.X[l15 * 512 + ((quad ^ (x7 & 3)) << 3)];
  const int x74s = (x7 & 4) << 3;
  const uchar_t* bL = sBw + quad * 512 + l15 * 8;

  float sumexp[3][4], labelA[3][4], blankV[3][4];
#pragma unroll
  for (int i = 0; i < 3; ++i)
#pragma unroll
    for (int j = 0; j < 4; ++j) { sumexp[i][j] = 0.0f; labelA[i][j] = 0.0f; blankV[i][j] = 0.0f; }

#pragma unroll 1
  for (int ct = 0; ct < 4; ++ct) {
    ffrag4 acc[3][4];
    ffrag4 zero4 = {0.0f, 0.0f, 0.0f, 0.0f};
#pragma unroll
    for (int rb = 0; rb < 3; ++rb)
#pragma unroll
      for (int cb = 0; cb < 4; ++cb) acc[rb][cb] = zero4;

#pragma unroll
    for (int ks = 0; ks < 16; ++ks) {
      if (ct < 3 || ks < 15) {
        STAGE(gP, (ks + 1) & 1)
        gP += 8192;
        asm volatile("s_waitcnt vmcnt(2)" ::: "memory");
      } else {
        asm volatile("s_waitcnt vmcnt(0)" ::: "memory");
      }
      const int aoff = (32 * ks) ^ x74s;
      lfrag av[3];
      av[0] = *(const lfrag*)(aL2 + aoff);
      av[1] = *(const lfrag*)(aL2 + aoff + 8192);
      av[2] = *(const lfrag*)(aL2 + aoff + 16384);
      const uchar_t* bk = bL + ((ks & 1) << 11);
      lfrag bv[4];
#pragma unroll
      for (int cb = 0; cb < 4; ++cb)
        bv[cb] = *(const lfrag*)(bk + cb * 128);
#pragma unroll
      for (int rb = 0; rb < 3; ++rb)
#pragma unroll
        for (int cb = 0; cb < 4; ++cb)
          acc[rb][cb] = __builtin_amdgcn_mfma_f32_16x16x32_fp8_fp8(av[rb], bv[cb], acc[rb][cb], 0, 0, 0);
    }

    // epilogue: acc = 16 x true logit; sumexp + raw label capture
#pragma unroll
    for (int cb = 0; cb < 4; ++cb) {
      const int v = ct * 256 + wave * 64 + cb * 16 + l15;
      const float bs = b2s[ct][cb];
#pragma unroll
      for (int rb = 0; rb < 3; ++rb)
#pragma unroll
        for (int reg = 0; reg < 4; ++reg) {
          float a = acc[rb][cb][reg];
          sumexp[rb][reg] += exp2f(fmaf(a, LOG2E16, bs));
          labelA[rb][reg] += (v == tokv[reg]) ? a : 0.0f;
        }
    }
    if (ct == 0 && wave == 0) {   // v==0 column lives on l15==0 lanes of cb 0
#pragma unroll
      for (int rb = 0; rb < 3; ++rb)
#pragma unroll
        for (int reg = 0; reg < 4; ++reg) blankV[rb][reg] = acc[rb][0][reg];
    }
  }
#undef STAGE

#pragma unroll
  for (int mask = 1; mask <= 8; mask <<= 1)
#pragma unroll
    for (int rb = 0; rb < 3; ++rb)
#pragma unroll
      for (int reg = 0; reg < 4; ++reg) {
        sumexp[rb][reg] += __shfl_xor(sumexp[rb][reg], mask, 64);
        labelA[rb][reg] += __shfl_xor(labelA[rb][reg], mask, 64);
      }

  __syncthreads();   // X reads done -> reuse union as red[]
  if (l15 == 0) {
#pragma unroll
    for (int rb = 0; rb < 3; ++rb)
#pragma unroll
      for (int reg = 0; reg < 4; ++reg) {
        int row = rb * 16 + quad * 4 + reg;
        sh.red[wave][row][0] = sumexp[rb][reg];
        sh.red[wave][row][1] = blankV[rb][reg];
        sh.red[wave][row][2] = labelA[rb][reg];
      }
  }
  __syncthreads();
  if (tid < ROWS) {
    float S  = sh.red[0][tid][0] + sh.red[1][tid][0] + sh.red[2][tid][0] + sh.red[3][tid][0];
    float Bl = sh.red[0][tid][1] + sh.red[1][tid][1] + sh.red[2][tid][1] + sh.red[3][tid][1];
    float Lb = sh.red[0][tid][2] + sh.red[1][tid][2] + sh.red[2][tid][2] + sh.red[3][tid][2];
    int t = t0 + (tid >> 2);
    int u = u0 + (tid & 3);
    if (t < T_DIM && u < U1) {
      float lse2 = __log2f(S);
      int tok = (u < U_DIM) ? tokens[b * U_DIM + u] : 0;
      size_t idx = (((size_t)(b * ND + t + u)) * 128 + u) * 2;
      pD[idx]     = fmaf(Bl, LOG2E16, b2[0]   * LOG2E) - lse2;   // blank (log2)
      pD[idx + 1] = fmaf(Lb, LOG2E16, b2[tok] * LOG2E) - lse2;   // label (log2)
    }
  }
}

// ---------------- RNNT DP (r10 structure): LDS DMA triple-buffer, batched
// chunk reads, DPP serial shuffles, log2 domain.
__global__ __launch_bounds__(256)
void dp_kernel(const float* __restrict__ pD,
               const int* __restrict__ outLen, const int* __restrict__ tokLen,
               float* __restrict__ outLoss)
{
  __shared__ __align__(16) float sD[4][3][CHUNK * 256];   // 96 KB
  __shared__ float llsh[B_DIM];
  const int tid = threadIdx.x;
  const int wv = tid >> 6;
  const int lane = tid & 63;
  const float* src = pD + (size_t)wv * ND * 256;
  const int tIdx = outLen[wv] - 1;
  const int uIdx = tokLen[wv];
  const int dStar = tIdx + uIdx;
  const float NEG = -1e30f;
  const float blkStar = src[((size_t)dStar * 128 + uIdx) * 2];

  float aE = (lane == 0) ? 0.0f : NEG;
  float aO = NEG;
  float ll2 = 0.0f;
  if (dStar == 0 && lane == 0) ll2 = blkStar;

  const int uE = 2 * lane;

#define ISSUE(c, buf)                                                         \
  {                                                                           \
    const float* g_ = src + (size_t)(c) * (CHUNK * 256);                      \
    float* l_ = &sD[wv][(buf)][0];                                            \
    _Pragma("unroll")                                                         \
    for (int j_ = 0; j_ < CHUNK; ++j_)                                        \
      __builtin_amdgcn_global_load_lds(                                       \
        (const AS1 void*)(g_ + j_ * 256 + lane * 4),                          \
        (AS3 void*)(l_ + j_ * 256), 16, 0, 0);                                \
  }

  ISSUE(0, 0)
  ISSUE(1, 1)
#pragma unroll 1
  for (int c = 0; c < 38; ++c) {
    { const int nc = c + 2; const int cc = nc <= 37 ? nc : 37; ISSUE(cc, nc % 3) }
    asm volatile("s_waitcnt vmcnt(16)" ::: "memory");   // chunk c resident
    const float* buf = &sD[wv][c % 3][0];
    float4 qv[CHUNK];
#pragma unroll
    for (int j = 0; j < CHUNK; ++j)
      qv[j] = *(const float4*)&buf[j * 256 + uE * 2];
#pragma unroll
    for (int j = 0; j < CHUNK; ++j) {
      const int d = c * CHUNK + 1 + j;
      float4 q = qv[j];
      float aO_up = dpp_up1(aO, NEG);
      float labUp = dpp_up1(q.w, NEG);                // L[uE-1] @ d-1
      float bt0 = aE + q.x, lt0 = aO_up + labUp;
      float mx0 = fmaxf(bt0, lt0), mn0 = fminf(bt0, lt0);
      float r0 = mx0 + __log2f(1.0f + exp2f(mn0 - mx0));
      int te = d - uE;
      float nE = ((uE <= U_DIM) && (te >= 0) && (te < T_DIM)) ? r0 : NEG;
      float bt1 = aO + q.z, lt1 = aE + q.y;
      float mx1 = fmaxf(bt1, lt1), mn1 = fminf(bt1, lt1);
      float r1 = mx1 + __log2f(1.0f + exp2f(mn1 - mx1));
      int to = te - 1;
      float nO = ((uE + 1 <= U_DIM) && (to >= 0) && (to < T_DIM)) ? r1 : NEG;
      aE = nE; aO = nO;
      if (d == dStar) {
        if (uIdx == uE)          ll2 = nE + blkStar;
        else if (uIdx == uE + 1) ll2 = nO + blkStar;
      }
    }
  }
#undef ISSUE

#pragma unroll
  for (int mask = 1; mask < 64; mask <<= 1) ll2 += __shfl_xor(ll2, mask, 64);
  if (lane == 0) llsh[wv] = ll2;
  __syncthreads();
  if (tid == 0)
    outLoss[0] = -(llsh[0] + llsh[1] + llsh[2] + llsh[3]) * 0.25f * LN2;
}

// ---------------- launch
extern "C" void kernel_launch(void* const* d_in, const int* in_sizes, int n_in,
                              void* d_out, int out_size, void* d_ws, size_t ws_size,
                              hipStream_t stream)
{
  const float* enc    = (const float*)d_in[0];
  const float* dec    = (const float*)d_in[1];
  const int*   tokens = (const int*)d_in[2];
  const int*   outLen = (const int*)d_in[3];
  const int*   tokLen = (const int*)d_in[4];
  const float* W1     = (const float*)d_in[5];
  const float* b1     = (const float*)d_in[6];
  const float* W2     = (const float*)d_in[7];
  const float* b2     = (const float*)d_in[8];
  float* out = (float*)d_out;

  char* ws = (char*)d_ws;
  float*   hEnc = (float*)(ws + 0);            // 1,638,400
  float*   hDec = (float*)(ws + 1638400);      //   827,392
  uchar_t* W2f8 = (uchar_t*)(ws + 2465792);    //   524,288
  uchar_t* Xg   = (uchar_t*)(ws + 2990080);    // 41,369,600 (+4KB overread pad)
  float*   pD   = (float*)(ws + 44363776);     // 1,228,800 (+16KB dp overread pad)
  // total ~45.6 MB

  prep_kernel<<<dim3(215), dim3(512), 0, stream>>>(enc, dec, W1, W2, hEnc, hDec, W2f8);
  xgen_kernel<<<dim3(20200), dim3(256), 0, stream>>>(hEnc, hDec, b1, Xg);
  joint_kernel<<<dim3(26, 17, B_DIM), dim3(256), 0, stream>>>(Xg, W2f8, b2, tokens, pD);
  dp_kernel<<<dim3(1), dim3(256), 0, stream>>>(pD, outLen, tokLen, out);
}